// Round 20
// baseline (398.595 us; speedup 1.0000x reference)
//
#include <hip/hip_runtime.h>
#include <hip/hip_bf16.h>
#include <cstdint>

#define TPB 256

typedef __attribute__((ext_vector_type(8))) short short8v;
typedef __attribute__((ext_vector_type(4))) float float4v;

#if __has_builtin(__builtin_amdgcn_global_load_lds)
#define GLDS(gp, lbase) __builtin_amdgcn_global_load_lds( \
    (const __attribute__((address_space(1))) void*)(gp), \
    (__attribute__((address_space(3))) void*)(lbase), 16, 0, 0)
#define GLDS_FALLBACK 0
#else
#define GLDS_FALLBACK 1
#define GLDS(gp, lbase) (void)0
#endif

__device__ inline ushort f2bf(float f) {
  union { float f; uint u; } c; c.f = f;
  uint b = c.u;
  return (ushort)((b + 0x7fffu + ((b >> 16) & 1u)) >> 16);
}
__device__ inline float bf2f(ushort u) {
  union { uint u; float f; } c; c.u = ((uint)u) << 16;
  return c.f;
}

// XCD-aware block swizzle (bijective when nbx % 8 == 0).
__device__ __forceinline__ int xcd_swz(int px, int nbx) {
  if (nbx & 7) return px;
  int q = nbx >> 3;
  return (px & 7) * q + (px >> 3);
}

// ---------------- init ----------------
__global__ __launch_bounds__(TPB) void k_init(int* deg_td, int* deg_bu, int* parent,
    float* pool_td, float* pool_bu, int* first, float* cnt, int N, int GH, int G) {
  int i = blockIdx.x * TPB + threadIdx.x;
  if (i < N) { deg_td[i] = 1; deg_bu[i] = 1; parent[i] = -1; }
  if (i < GH) { pool_td[i] = 0.f; pool_bu[i] = 0.f; }
  if (i < G) { first[i] = 0x7fffffff; cnt[i] = 0.f; }
}

// ---------------- stats: LDS histogram ----------------
__global__ __launch_bounds__(TPB) void k_stats(const int* __restrict__ batch,
    int* first, float* cnt, int N, int G) {
  __shared__ int h[1024];
  __shared__ int fm[1024];
  if (G <= 1024) {
    for (int t = threadIdx.x; t < G; t += TPB) { h[t] = 0; fm[t] = 0x7fffffff; }
    __syncthreads();
    int i = blockIdx.x * TPB + threadIdx.x;
    if (i < N) { int g = batch[i]; atomicAdd(&h[g], 1); atomicMin(&fm[g], i); }
    __syncthreads();
    for (int t = threadIdx.x; t < G; t += TPB) {
      if (h[t]) { atomicAdd(&cnt[t], (float)h[t]); atomicMin(&first[t], fm[t]); }
    }
  } else {
    int i = blockIdx.x * TPB + threadIdx.x;
    if (i < N) { int g = batch[i]; atomicMin(&first[g], i); atomicAdd(&cnt[g], 1.f); }
  }
}

__global__ __launch_bounds__(TPB) void k_deg(const int* __restrict__ s,
    const int* __restrict__ d, int* deg_td, int* deg_bu, int* parent, int E) {
  int e = blockIdx.x * TPB + threadIdx.x;
  if (e < E) {
    atomicAdd(&deg_td[d[e]], 1);
    atomicAdd(&deg_bu[s[e]], 1);
    parent[d[e]] = s[e];  // dst unique (tree) -> race-free
  }
}

// ---------------- CSR build: scan of (deg_bu - 1); dinv folded in ----------------
__global__ __launch_bounds__(TPB) void k_scan1(const int* __restrict__ deg_td,
    const int* __restrict__ deg_bu, float* dinv_td, float* dinv_bu,
    int* bsum, int N) {
  __shared__ int s[TPB];
  int i = blockIdx.x * TPB + threadIdx.x;
  int d = (i < N) ? deg_bu[i] : 1;
  s[threadIdx.x] = d - 1;
  if (i < N) {
    dinv_td[i] = rsqrtf((float)deg_td[i]);
    dinv_bu[i] = rsqrtf((float)d);
  }
  __syncthreads();
  for (int off = TPB / 2; off > 0; off >>= 1) {
    if (threadIdx.x < off) s[threadIdx.x] += s[threadIdx.x + off];
    __syncthreads();
  }
  if (threadIdx.x == 0) bsum[blockIdx.x] = s[0];
}

__global__ __launch_bounds__(1024) void k_scan2(int* bsum, int NB) {
  __shared__ int s[1024];
  int t = threadIdx.x;
  int own = (t < NB) ? bsum[t] : 0;
  s[t] = own;
  __syncthreads();
  for (int off = 1; off < 1024; off <<= 1) {
    int v = (t >= off) ? s[t - off] : 0;
    __syncthreads();
    s[t] += v;
    __syncthreads();
  }
  if (t < NB) bsum[t] = s[t] - own;  // exclusive
}

__global__ __launch_bounds__(TPB) void k_scan3(const int* __restrict__ deg,
    const int* __restrict__ bsum, int* offs, int* cursor, int N) {
  __shared__ int s[TPB];
  int t = threadIdx.x;
  int i = blockIdx.x * TPB + t;
  int v = (i < N) ? deg[i] - 1 : 0;
  s[t] = v;
  __syncthreads();
  for (int off = 1; off < TPB; off <<= 1) {
    int u = (t >= off) ? s[t - off] : 0;
    __syncthreads();
    s[t] += u;
    __syncthreads();
  }
  int excl = bsum[blockIdx.x] + s[t] - v;
  if (i < N) {
    offs[i] = excl;
    cursor[i] = excl;
    if (i == N - 1) offs[N] = excl + v;
  }
}

__global__ __launch_bounds__(TPB) void k_fill(const int* __restrict__ s,
    const int* __restrict__ d, int* cursor, int* childs, int E) {
  int e = blockIdx.x * TPB + threadIdx.x;
  if (e < E) {
    int pos = atomicAdd(&cursor[s[e]], 1);
    childs[pos] = d[e];
  }
}

// ---------------- root projection (f32, tiny) ----------------
__global__ __launch_bounds__(64) void k_root(const float* __restrict__ x,
    const int* __restrict__ first, const float* __restrict__ W2_td,
    const float* __restrict__ W2_bu, float* R_td, float* R_bu, int F, int H) {
  __shared__ float xr[256];
  int g = blockIdx.x;
  int c = blockIdx.y * 64 + threadIdx.x;
  int root = first[g];
  for (int k = threadIdx.x; k < F; k += 64) xr[k] = fmaxf(x[(size_t)root * F + k], 0.f);
  __syncthreads();
  float atd = 0.f, abu = 0.f;
  for (int k = 0; k < F; ++k) {
    float v = xr[k];
    atd += v * W2_td[(size_t)(H + k) * H + c];
    abu += v * W2_bu[(size_t)(H + k) * H + c];
  }
  R_td[(size_t)g * H + c] = atd;
  R_bu[(size_t)g * H + c] = abu;
}

// ---------------- transpose-cast 4 weights in one launch ----------------
__global__ __launch_bounds__(TPB) void k_prep_w4(
    const float* __restrict__ W0, const float* __restrict__ W1,
    const float* __restrict__ W2, const float* __restrict__ W3,
    ushort* __restrict__ T0, ushort* __restrict__ T1,
    ushort* __restrict__ T2, ushort* __restrict__ T3, int K, int Nn) {
  int total = K * Nn;
  int idx = blockIdx.x * TPB + threadIdx.x;
  int w = idx / total;
  idx -= w * total;
  if (w >= 4) return;
  const float* W = (w == 0) ? W0 : (w == 1) ? W1 : (w == 2) ? W2 : W3;
  ushort* T = (w == 0) ? T0 : (w == 1) ? T1 : (w == 2) ? T2 : T3;
  int k = idx / Nn;
  int n = idx - k * Nn;
  T[(size_t)n * K + k] = f2bf(W[(size_t)k * Nn + n]);
}

// ============ layer-1 DUAL GEMM: A (f32, inline cast) staged ONCE, two B ============
__global__ __launch_bounds__(512, 2) void gemm_l1_dual(
    const float* __restrict__ X,
    const ushort* __restrict__ Bt0, const ushort* __restrict__ Bt1,
    ushort* __restrict__ C0, ushort* __restrict__ C1) {
  __shared__ ushort lA[2 * 4096];    // 16 KB
  __shared__ ushort lB0[2 * 8192];   // 32 KB
  __shared__ ushort lB1[2 * 8192];   // 32 KB
  const int tid = threadIdx.x;
  const int wid = tid >> 6;
  const int wr = wid >> 2;
  const int wc = wid & 3;
  const int lane = tid & 63;
  const int lr = lane & 15;
  const int lkq = lane >> 4;
  const int m0 = blockIdx.x * 128;

  const int arow = m0 + (tid >> 6) * 16 + (lane & 15);
  const size_t abase = (size_t)arow * 256 + lkq * 8;
  const size_t boff0 = (size_t)((tid >> 6) * 16 + lr) * 256 + lkq * 8;
  const size_t boff1 = (size_t)((8 + (tid >> 6)) * 16 + lr) * 256 + lkq * 8;
  const int cw = tid & ~63;

  float4v acc0[4][4], acc1[4][4];
#pragma unroll
  for (int rf = 0; rf < 4; ++rf)
#pragma unroll
    for (int t = 0; t < 4; ++t) { acc0[rf][t] = (float4v)0.f; acc1[rf][t] = (float4v)0.f; }

  float4 a0v, a1v;
  a0v = *(const float4*)&X[abase];
  a1v = *(const float4*)&X[abase + 4];
#if GLDS_FALLBACK
  *(uint4*)&lB0[(0 * 1024 + tid) * 8] = *(const uint4*)&Bt0[boff0];
  *(uint4*)&lB0[(0 * 1024 + 512 + tid) * 8] = *(const uint4*)&Bt0[boff1];
  *(uint4*)&lB1[(0 * 1024 + tid) * 8] = *(const uint4*)&Bt1[boff0];
  *(uint4*)&lB1[(0 * 1024 + 512 + tid) * 8] = *(const uint4*)&Bt1[boff1];
#else
  GLDS(&Bt0[boff0], &lB0[(size_t)(0 * 1024 + cw) * 8]);
  GLDS(&Bt0[boff1], &lB0[(size_t)(0 * 1024 + 512 + cw) * 8]);
  GLDS(&Bt1[boff0], &lB1[(size_t)(0 * 1024 + cw) * 8]);
  GLDS(&Bt1[boff1], &lB1[(size_t)(0 * 1024 + 512 + cw) * 8]);
#endif
  {
    ushort u[8];
    u[0] = f2bf(a0v.x); u[1] = f2bf(a0v.y); u[2] = f2bf(a0v.z); u[3] = f2bf(a0v.w);
    u[4] = f2bf(a1v.x); u[5] = f2bf(a1v.y); u[6] = f2bf(a1v.z); u[7] = f2bf(a1v.w);
    *(uint4*)&lA[(size_t)(0 * 512 + tid) * 8] = *(const uint4*)u;
  }
  __syncthreads();

#pragma unroll
  for (int t = 0; t < 8; ++t) {
    const int cur = t & 1;
    if (t < 7) {
      const int k1 = (t + 1) * 32;
      a0v = *(const float4*)&X[abase + k1];
      a1v = *(const float4*)&X[abase + k1 + 4];
#if GLDS_FALLBACK
      *(uint4*)&lB0[(size_t)((cur ^ 1) * 1024 + tid) * 8] = *(const uint4*)&Bt0[boff0 + k1];
      *(uint4*)&lB0[(size_t)((cur ^ 1) * 1024 + 512 + tid) * 8] = *(const uint4*)&Bt0[boff1 + k1];
      *(uint4*)&lB1[(size_t)((cur ^ 1) * 1024 + tid) * 8] = *(const uint4*)&Bt1[boff0 + k1];
      *(uint4*)&lB1[(size_t)((cur ^ 1) * 1024 + 512 + tid) * 8] = *(const uint4*)&Bt1[boff1 + k1];
#else
      GLDS(&Bt0[boff0 + k1], &lB0[(size_t)((cur ^ 1) * 1024 + cw) * 8]);
      GLDS(&Bt0[boff1 + k1], &lB0[(size_t)((cur ^ 1) * 1024 + 512 + cw) * 8]);
      GLDS(&Bt1[boff0 + k1], &lB1[(size_t)((cur ^ 1) * 1024 + cw) * 8]);
      GLDS(&Bt1[boff1 + k1], &lB1[(size_t)((cur ^ 1) * 1024 + 512 + cw) * 8]);
#endif
    }
    short8v af[4], bf0[4], bf1[4];
#pragma unroll
    for (int rf = 0; rf < 4; ++rf)
      af[rf] = *(const short8v*)&lA[(size_t)(cur * 512 + (wr * 4 + rf) * 64 + lane) * 8];
#pragma unroll
    for (int tt = 0; tt < 4; ++tt) {
      bf0[tt] = *(const short8v*)&lB0[(size_t)(cur * 1024 + (wc * 4 + tt) * 64 + lane) * 8];
      bf1[tt] = *(const short8v*)&lB1[(size_t)(cur * 1024 + (wc * 4 + tt) * 64 + lane) * 8];
    }
#pragma unroll
    for (int rf = 0; rf < 4; ++rf)
#pragma unroll
      for (int tt = 0; tt < 4; ++tt) {
        acc0[rf][tt] = __builtin_amdgcn_mfma_f32_16x16x32_bf16(af[rf], bf0[tt], acc0[rf][tt], 0, 0, 0);
        acc1[rf][tt] = __builtin_amdgcn_mfma_f32_16x16x32_bf16(af[rf], bf1[tt], acc1[rf][tt], 0, 0, 0);
      }
    if (t < 7) {
      ushort u[8];
      u[0] = f2bf(a0v.x); u[1] = f2bf(a0v.y); u[2] = f2bf(a0v.z); u[3] = f2bf(a0v.w);
      u[4] = f2bf(a1v.x); u[5] = f2bf(a1v.y); u[6] = f2bf(a1v.z); u[7] = f2bf(a1v.w);
      *(uint4*)&lA[(size_t)((cur ^ 1) * 512 + tid) * 8] = *(const uint4*)u;
    }
    __syncthreads();
  }

#pragma unroll
  for (int rf = 0; rf < 4; ++rf) {
#pragma unroll
    for (int r = 0; r < 4; ++r) {
      const int row = m0 + wr * 64 + rf * 16 + lkq * 4 + r;
#pragma unroll
      for (int t = 0; t < 4; ++t) {
        const int col = wc * 64 + t * 16 + lr;
        C0[(size_t)row * 256 + col] = f2bf(acc0[rf][t][r]);
        C1[(size_t)row * 256 + col] = f2bf(acc1[rf][t][r]);
      }
    }
  }
}

// ============ layer-2 GEMM with conv1 PREPASS body (BM=64 BN=256) ============
// Meta (parent/offs/dinv/bias) loaded DIRECTLY per-thread (L1-broadcast) — no
// LDS staging, no meta barrier: gather loads issue as soon as the 4B index
// returns, shortening the prepass dependency chain by a barrier + LDS trip.
template <bool CSR>
__device__ __forceinline__ void l2f_body(
    ushort* lA, ushort* lB,
    const ushort* __restrict__ XW, const ushort* __restrict__ Bt,
    ushort* __restrict__ Cbf, const float* __restrict__ Rb,
    const int* __restrict__ batch, const int* __restrict__ parent,
    const int* __restrict__ offs, const int* __restrict__ childs,
    const float* __restrict__ dinv, const float* __restrict__ bias, int m0) {
  const int tid = threadIdx.x;
  const int wid = tid >> 6;
  const int wr = wid >> 2;        // 0..1
  const int wc = wid & 3;         // 0..3
  const int lane = tid & 63;
  const int lr = lane & 15;
  const int lkq = lane >> 4;

  const size_t boff0 = (size_t)((tid >> 6) * 16 + lr) * 256 + lkq * 8;
  const size_t boff1 = (size_t)((8 + (tid >> 6)) * 16 + lr) * 256 + lkq * 8;
  const int cw = tid & ~63;
#if GLDS_FALLBACK
  *(uint4*)&lB[(size_t)(0 * 1024 + tid) * 8] = *(const uint4*)&Bt[boff0];
  *(uint4*)&lB[(size_t)(0 * 1024 + 512 + tid) * 8] = *(const uint4*)&Bt[boff1];
#else
  GLDS(&Bt[boff0], &lB[(size_t)(0 * 1024 + cw) * 8]);
  GLDS(&Bt[boff1], &lB[(size_t)(0 * 1024 + 512 + cw) * 8]);
#endif

  // ---- prepass: conv1(XW) -> lA (coalesced reads, padded-group writes) ----
  {
    const int rl = tid >> 3;       // 0..63 local row
    const int o  = tid & 7;        // 32-col slab
    const int grow = m0 + rl;
    const int cbase = o * 32;
    const float di = dinv[grow];
    uint4 ox[4];
#pragma unroll
    for (int j = 0; j < 4; ++j)
      ox[j] = *(const uint4*)&XW[(size_t)grow * 256 + cbase + j * 8];
    float a[4][8];
    if (!CSR) {
      const int p = parent[grow];
      const int pp = (p >= 0) ? p : 0;
      const float dp = (p >= 0) ? dinv[pp] : 0.f;
      uint4 pu[4];
#pragma unroll
      for (int j = 0; j < 4; ++j)
        pu[j] = *(const uint4*)&XW[(size_t)pp * 256 + cbase + j * 8];
#pragma unroll
      for (int j = 0; j < 4; ++j) {
        const ushort* o8 = (const ushort*)&ox[j];
        const ushort* q8 = (const ushort*)&pu[j];
#pragma unroll
        for (int e = 0; e < 8; ++e)
          a[j][e] = bf2f(o8[e]) * di + bf2f(q8[e]) * dp;
      }
    } else {
#pragma unroll
      for (int j = 0; j < 4; ++j) {
        const ushort* o8 = (const ushort*)&ox[j];
#pragma unroll
        for (int e = 0; e < 8; ++e) a[j][e] = bf2f(o8[e]) * di;
      }
      const int k0 = offs[grow], k1 = offs[grow + 1];
      for (int k = k0; k < k1; ++k) {
        int c = childs[k];
        float dc = dinv[c];
        uint4 cu[4];
#pragma unroll
        for (int j = 0; j < 4; ++j)
          cu[j] = *(const uint4*)&XW[(size_t)c * 256 + cbase + j * 8];
#pragma unroll
        for (int j = 0; j < 4; ++j) {
          const ushort* u8 = (const ushort*)&cu[j];
#pragma unroll
          for (int e = 0; e < 8; ++e) a[j][e] += bf2f(u8[e]) * dc;
        }
      }
    }
    const int rfg = rl >> 4, l15 = rl & 15;
    const int grp = rfg * 8 + o;
#pragma unroll
    for (int j = 0; j < 4; ++j) {
      const float4 bj0 = *(const float4*)&bias[cbase + j * 8];
      const float4 bj1 = *(const float4*)&bias[cbase + j * 8 + 4];
      const float bb[8] = {bj0.x, bj0.y, bj0.z, bj0.w, bj1.x, bj1.y, bj1.z, bj1.w};
      ushort res[8];
#pragma unroll
      for (int e = 0; e < 8; ++e)
        res[e] = f2bf(fmaxf(bb[e] + di * a[j][e], 0.f));
      *(uint4*)&lA[(size_t)(grp * 65 + j * 16 + l15) * 8] = *(const uint4*)res;
    }
  }
  __syncthreads();

  // ---- main loop: 8 K-steps, A from lA (padded groups), B double-buffered ----
  float4v acc[2][4];
#pragma unroll
  for (int rf = 0; rf < 2; ++rf)
#pragma unroll
    for (int t = 0; t < 4; ++t) acc[rf][t] = (float4v)0.f;

#pragma unroll
  for (int t = 0; t < 8; ++t) {
    const int cur = t & 1;
    if (t < 7) {
      const int k1 = (t + 1) * 32;
#if GLDS_FALLBACK
      *(uint4*)&lB[(size_t)((cur ^ 1) * 1024 + tid) * 8] = *(const uint4*)&Bt[boff0 + k1];
      *(uint4*)&lB[(size_t)((cur ^ 1) * 1024 + 512 + tid) * 8] = *(const uint4*)&Bt[boff1 + k1];
#else
      GLDS(&Bt[boff0 + k1], &lB[(size_t)((cur ^ 1) * 1024 + cw) * 8]);
      GLDS(&Bt[boff1 + k1], &lB[(size_t)((cur ^ 1) * 1024 + 512 + cw) * 8]);
#endif
    }
    short8v af[2], bfv[4];
#pragma unroll
    for (int rf = 0; rf < 2; ++rf)
      af[rf] = *(const short8v*)&lA[(size_t)((((wr * 2 + rf) * 8 + t) * 65) + lane) * 8];
#pragma unroll
    for (int tt = 0; tt < 4; ++tt)
      bfv[tt] = *(const short8v*)&lB[(size_t)(cur * 1024 + (wc * 4 + tt) * 64 + lane) * 8];
#pragma unroll
    for (int rf = 0; rf < 2; ++rf)
#pragma unroll
      for (int tt = 0; tt < 4; ++tt)
        acc[rf][tt] = __builtin_amdgcn_mfma_f32_16x16x32_bf16(af[rf], bfv[tt], acc[rf][tt], 0, 0, 0);
    __syncthreads();
  }

  // ---- epilogue: + R[batch], bf16 store ----
#pragma unroll
  for (int rf = 0; rf < 2; ++rf) {
#pragma unroll
    for (int r = 0; r < 4; ++r) {
      const int row = m0 + wr * 32 + rf * 16 + lkq * 4 + r;
      const float* rb = &Rb[(size_t)batch[row] * 256];
#pragma unroll
      for (int tt = 0; tt < 4; ++tt) {
        const int col = wc * 64 + tt * 16 + lr;
        Cbf[(size_t)row * 256 + col] = f2bf(acc[rf][tt][r] + rb[col]);
      }
    }
  }
}

// both directions in ONE dispatch (independent work, tails overlap)
__global__ __launch_bounds__(512, 2) void gemm_l2f_pair(
    const ushort* __restrict__ XW0, const ushort* __restrict__ XW1,
    const ushort* __restrict__ Bt0, const ushort* __restrict__ Bt1,
    ushort* __restrict__ C0, ushort* __restrict__ C1,
    const float* __restrict__ R0, const float* __restrict__ R1,
    const int* __restrict__ batch, const int* __restrict__ parent,
    const int* __restrict__ offs, const int* __restrict__ childs,
    const float* __restrict__ dinv0, const float* __restrict__ dinv1,
    const float* __restrict__ b0, const float* __restrict__ b1) {
  __shared__ ushort lA[32 * 65 * 8];  // 33280 B
  __shared__ ushort lB[2 * 8192];     // 32 KB
  const int m0 = blockIdx.x * 64;
  if (blockIdx.y == 0)
    l2f_body<false>(lA, lB, XW0, Bt0, C0, R0, batch, parent, offs, childs, dinv0, b0, m0);
  else
    l2f_body<true>(lA, lB, XW1, Bt1, C1, R1, batch, parent, offs, childs, dinv1, b1, m0);
}

// ---------------- conv layer2 + pool body: 128 nodes/block, ILP-4, register pooling ----------------
template <bool CSR>
__device__ __forceinline__ void conv2_body(int bx, float (*s)[256],
    const ushort* __restrict__ xw, float* __restrict__ pool,
    const int* __restrict__ parent, const int* __restrict__ offs,
    const int* __restrict__ childs, const float* __restrict__ dinv,
    const float* __restrict__ bias, const int* __restrict__ batch, int N) {
  const int l = threadIdx.x & 31;
  const int c8 = l * 8;
  const int hw = threadIdx.x >> 5;
  const int base = bx * 128;
  if (base >= N) return;
  const int nmax = min(base + 128, N);
  const int g0 = batch[base];
  const bool uni = (batch[nmax - 1] == g0);
  float bseg[8];
  *(float4*)&bseg[0] = *(const float4*)(bias + c8);
  *(float4*)&bseg[4] = *(const float4*)(bias + c8 + 4);
  float acc[8];
#pragma unroll
  for (int j = 0; j < 8; ++j) acc[j] = 0.f;
  for (int it0 = 0; it0 < 16; it0 += 4) {
    uint4 own[4]; float di[4]; int aux[4], k1v[4], nds[4];
#pragma unroll
    for (int i = 0; i < 4; ++i) {
      int nd = base + (it0 + i) * 8 + hw;
      nds[i] = nd;
      int ndc = min(nd, N - 1);
      own[i] = *(const uint4*)(xw + (size_t)ndc * 256 + c8);
      di[i] = dinv[ndc];
      if (CSR) { aux[i] = offs[ndc]; k1v[i] = offs[ndc + 1]; }
      else { aux[i] = parent[ndc]; }
    }
    uint4 par[4]; float dp[4];
    if (!CSR) {
#pragma unroll
      for (int i = 0; i < 4; ++i) {
        int p = aux[i];
        int pp = p >= 0 ? p : 0;
        par[i] = *(const uint4*)(xw + (size_t)pp * 256 + c8);
        dp[i] = p >= 0 ? dinv[pp] : 0.f;
      }
    }
#pragma unroll
    for (int i = 0; i < 4; ++i) {
      if (nds[i] >= N) break;
      const ushort* o = (const ushort*)&own[i];
      float y[8];
      if (!CSR) {
        const ushort* q = (const ushort*)&par[i];
#pragma unroll
        for (int j = 0; j < 8; ++j) {
          float a = bf2f(o[j]) * di[i] + bf2f(q[j]) * dp[i];
          y[j] = fmaxf(bseg[j] + di[i] * a, 0.f);
        }
      } else {
        float a[8];
#pragma unroll
        for (int j = 0; j < 8; ++j) a[j] = bf2f(o[j]) * di[i];
        for (int k = aux[i]; k < k1v[i]; ++k) {
          int c = childs[k];
          float dc = dinv[c];
          uint4 u = *(const uint4*)(xw + (size_t)c * 256 + c8);
          const ushort* uu = (const ushort*)&u;
#pragma unroll
          for (int j = 0; j < 8; ++j) a[j] += bf2f(uu[j]) * dc;
        }
#pragma unroll
        for (int j = 0; j < 8; ++j) y[j] = fmaxf(bseg[j] + di[i] * a[j], 0.f);
      }
      if (uni) {
#pragma unroll
        for (int j = 0; j < 8; ++j) acc[j] += y[j];
      } else {
        int g = batch[nds[i]];
#pragma unroll
        for (int j = 0; j < 8; ++j) atomicAdd(&pool[(size_t)g * 256 + c8 + j], y[j]);
      }
    }
  }
  if (uni) {
    *(float4*)&s[hw][c8] = *(float4*)&acc[0];
    *(float4*)&s[hw][c8 + 4] = *(float4*)&acc[4];
    __syncthreads();
    int col = threadIdx.x;
    float v = 0.f;
#pragma unroll
    for (int q = 0; q < 8; ++q) v += s[q][col];
    atomicAdd(&pool[(size_t)g0 * 256 + col], v);
  }
}

__global__ __launch_bounds__(TPB) void k_conv2_pair(
    const ushort* __restrict__ xwA, const ushort* __restrict__ xwB,
    float* __restrict__ pool_td, float* __restrict__ pool_bu,
    const int* __restrict__ parent, const int* __restrict__ offs,
    const int* __restrict__ childs, const float* __restrict__ dinv_td,
    const float* __restrict__ dinv_bu, const float* __restrict__ b_td,
    const float* __restrict__ b_bu, const int* __restrict__ batch, int N) {
  __shared__ float s[8][256];
  const int bx = xcd_swz(blockIdx.x, gridDim.x);
  if (blockIdx.y == 0)
    conv2_body<false>(bx, s, xwA, pool_td, parent, offs, childs, dinv_td, b_td, batch, N);
  else
    conv2_body<true>(bx, s, xwB, pool_bu, parent, offs, childs, dinv_bu, b_bu, batch, N);
}

// ---------------- head ----------------
__global__ __launch_bounds__(128) void k_head(const float* __restrict__ pool_td,
    const float* __restrict__ pool_bu, const float* __restrict__ cnt,
    const float* __restrict__ Wl, const float* __restrict__ bl,
    float* __restrict__ out, int H, int C) {
  int g = blockIdx.x;
  int t = threadIdx.x;
  float inv = 1.f / cnt[g];
  float acc[8];
  for (int c = 0; c < C; ++c) acc[c] = 0.f;
  int twoH = 2 * H;
  for (int d0 = t; d0 < twoH; d0 += 128) {
    float v = (d0 < H ? pool_td[(size_t)g * H + d0] : pool_bu[(size_t)g * H + d0 - H]) * inv;
    for (int c = 0; c < C; ++c) acc[c] += v * Wl[(size_t)d0 * C + c];
  }
  __shared__ float red[128 * 8];
  for (int c = 0; c < C; ++c) red[t * C + c] = acc[c];
  __syncthreads();
  for (int off = 64; off > 0; off >>= 1) {
    if (t < off)
      for (int c = 0; c < C; ++c) red[t * C + c] += red[(t + off) * C + c];
    __syncthreads();
  }
  if (t == 0) {
    float l[8];
    float m = -1e30f;
    for (int c = 0; c < C; ++c) { l[c] = red[c] + bl[c]; m = fmaxf(m, l[c]); }
    float ssum = 0.f;
    for (int c = 0; c < C; ++c) ssum += expf(l[c] - m);
    float ls = logf(ssum);
    for (int c = 0; c < C; ++c) out[(size_t)g * C + c] = l[c] - m - ls;
  }
}

extern "C" void kernel_launch(void* const* d_in, const int* in_sizes, int n_in,
                              void* d_out, int out_size, void* d_ws, size_t ws_size,
                              hipStream_t stream) {
  const float* x     = (const float*)d_in[0];
  const int*   ei    = (const int*)d_in[1];
  const int*   batch = (const int*)d_in[2];
  const float* W1_td = (const float*)d_in[4];
  const float* b1_td = (const float*)d_in[5];
  const float* W1_bu = (const float*)d_in[6];
  const float* b1_bu = (const float*)d_in[7];
  const float* W2_td = (const float*)d_in[8];
  const float* b2_td = (const float*)d_in[9];
  const float* W2_bu = (const float*)d_in[10];
  const float* b2_bu = (const float*)d_in[11];
  const float* Wl    = (const float*)d_in[12];
  const float* bl    = (const float*)d_in[13];
  float* out = (float*)d_out;

  const int N = in_sizes[2];
  const int H = in_sizes[5];
  const int F = in_sizes[0] / N;
  const int E = in_sizes[1] / 2;
  const int C = in_sizes[13];
  const int G = out_size / C;

  const int* srcp = ei;
  const int* dstp = ei + E;

  const size_t NH = (size_t)N * H;
  const size_t KH = (size_t)F * H;

  ushort* bufA   = (ushort*)d_ws;                 // N*H  xw_td
  ushort* bufB   = bufA + NH;                     // N*H  h2_td
  ushort* bufC   = bufB + NH;                     // N*H  xw_bu
  ushort* bufD   = bufC + NH;                     // N*H  h2_bu
  ushort* Wt1_td = bufD + NH;                     // F*H each
  ushort* Wt1_bu = Wt1_td + KH;
  ushort* Wt2_td = Wt1_bu + KH;
  ushort* Wt2_bu = Wt2_td + KH;
  float* dinv_td = (float*)(Wt2_bu + KH);         // N
  float* dinv_bu = dinv_td + N;                   // N
  float* R_td    = dinv_bu + N;                   // G*H
  float* R_bu    = R_td + (size_t)G * H;
  float* pool_td = R_bu + (size_t)G * H;
  float* pool_bu = pool_td + (size_t)G * H;
  float* cnt     = pool_bu + (size_t)G * H;       // G
  int* deg_td    = (int*)(cnt + G);               // N
  int* deg_bu    = deg_td + N;                    // N
  int* parent    = deg_bu + N;                    // N
  int* offs      = parent + N;                    // N+1
  int* cursor    = offs + N + 1;                  // N
  int* childs    = cursor + N;                    // E
  int* bsum      = childs + E;                    // NB
  int* first     = bsum + 1024;                   // G
  size_t need = (size_t)((char*)(first + G) - (char*)d_ws);
  if (need > ws_size) return;

  const int nbN = (N + TPB - 1) / TPB;  // also NB for scan
  const int nbE = (E + TPB - 1) / TPB;
  const int GH = G * H;
  const int nbW4 = (int)((4 * KH + TPB - 1) / TPB);
  const dim3 gemmGrid(N / 128);
  const dim3 gemm2Grid(N / 64, 2);
  const dim3 conv2Grid((N + 127) / 128, 2);

  k_init<<<nbN, TPB, 0, stream>>>(deg_td, deg_bu, parent, pool_td, pool_bu, first, cnt, N, GH, G);
  k_stats<<<nbN, TPB, 0, stream>>>(batch, first, cnt, N, G);
  k_deg<<<nbE, TPB, 0, stream>>>(srcp, dstp, deg_td, deg_bu, parent, E);
  k_scan1<<<nbN, TPB, 0, stream>>>(deg_td, deg_bu, dinv_td, dinv_bu, bsum, N);
  k_scan2<<<1, 1024, 0, stream>>>(bsum, nbN);
  k_scan3<<<nbN, TPB, 0, stream>>>(deg_bu, bsum, offs, cursor, N);
  k_fill<<<nbE, TPB, 0, stream>>>(srcp, dstp, cursor, childs, E);

  k_root<<<dim3(G, H / 64), 64, 0, stream>>>(x, first, W2_td, W2_bu, R_td, R_bu, F, H);
  k_prep_w4<<<nbW4, TPB, 0, stream>>>(W1_td, W1_bu, W2_td, W2_bu,
                                      Wt1_td, Wt1_bu, Wt2_td, Wt2_bu, F, H);

  // ---- layer 1: DUAL fused cast + GEMM (x read once) ----
  gemm_l1_dual<<<gemmGrid, 512, 0, stream>>>(x, Wt1_td, Wt1_bu, bufA, bufC);

  // ---- layer 2: both directions, conv1 prepass fused, ONE dispatch ----
  gemm_l2f_pair<<<gemm2Grid, 512, 0, stream>>>(bufA, bufC, Wt2_td, Wt2_bu,
      bufB, bufD, R_td, R_bu, batch, parent, offs, childs,
      dinv_td, dinv_bu, b1_td, b1_bu);

  // ---- conv2 + pool both (128 nodes/block, ILP-4, XCD-swizzled) ----
  k_conv2_pair<<<conv2Grid, TPB, 0, stream>>>(bufB, bufD, pool_td, pool_bu,
      parent, offs, childs, dinv_td, dinv_bu, b2_td, b2_bu, batch, N);

  k_head<<<G, 128, 0, stream>>>(pool_td, pool_bu, cnt, Wl, bl, out, H, C);
}

// Round 21
// 383.792 us; speedup vs baseline: 1.0386x; 1.0386x over previous
//
#include <hip/hip_runtime.h>
#include <hip/hip_bf16.h>
#include <cstdint>

#define TPB 256

typedef __attribute__((ext_vector_type(8))) short short8v;
typedef __attribute__((ext_vector_type(4))) float float4v;

#if __has_builtin(__builtin_amdgcn_global_load_lds)
#define GLDS(gp, lbase) __builtin_amdgcn_global_load_lds( \
    (const __attribute__((address_space(1))) void*)(gp), \
    (__attribute__((address_space(3))) void*)(lbase), 16, 0, 0)
#define GLDS_FALLBACK 0
#else
#define GLDS_FALLBACK 1
#define GLDS(gp, lbase) (void)0
#endif

__device__ inline ushort f2bf(float f) {
  union { float f; uint u; } c; c.f = f;
  uint b = c.u;
  return (ushort)((b + 0x7fffu + ((b >> 16) & 1u)) >> 16);
}
__device__ inline float bf2f(ushort u) {
  union { uint u; float f; } c; c.u = ((uint)u) << 16;
  return c.f;
}

// XCD-aware block swizzle (bijective when nbx % 8 == 0).
__device__ __forceinline__ int xcd_swz(int px, int nbx) {
  if (nbx & 7) return px;
  int q = nbx >> 3;
  return (px & 7) * q + (px >> 3);
}

// ---------------- init ----------------
__global__ __launch_bounds__(TPB) void k_init(int* deg_td, int* deg_bu, int* parent,
    float* pool_td, float* pool_bu, int* first, float* cnt, int N, int GH, int G) {
  int i = blockIdx.x * TPB + threadIdx.x;
  if (i < N) { deg_td[i] = 1; deg_bu[i] = 1; parent[i] = -1; }
  if (i < GH) { pool_td[i] = 0.f; pool_bu[i] = 0.f; }
  if (i < G) { first[i] = 0x7fffffff; cnt[i] = 0.f; }
}

// ---------------- stats: LDS histogram ----------------
__global__ __launch_bounds__(TPB) void k_stats(const int* __restrict__ batch,
    int* first, float* cnt, int N, int G) {
  __shared__ int h[1024];
  __shared__ int fm[1024];
  if (G <= 1024) {
    for (int t = threadIdx.x; t < G; t += TPB) { h[t] = 0; fm[t] = 0x7fffffff; }
    __syncthreads();
    int i = blockIdx.x * TPB + threadIdx.x;
    if (i < N) { int g = batch[i]; atomicAdd(&h[g], 1); atomicMin(&fm[g], i); }
    __syncthreads();
    for (int t = threadIdx.x; t < G; t += TPB) {
      if (h[t]) { atomicAdd(&cnt[t], (float)h[t]); atomicMin(&first[t], fm[t]); }
    }
  } else {
    int i = blockIdx.x * TPB + threadIdx.x;
    if (i < N) { int g = batch[i]; atomicMin(&first[g], i); atomicAdd(&cnt[g], 1.f); }
  }
}

__global__ __launch_bounds__(TPB) void k_deg(const int* __restrict__ s,
    const int* __restrict__ d, int* deg_td, int* deg_bu, int* parent, int E) {
  int e = blockIdx.x * TPB + threadIdx.x;
  if (e < E) {
    atomicAdd(&deg_td[d[e]], 1);
    atomicAdd(&deg_bu[s[e]], 1);
    parent[d[e]] = s[e];  // dst unique (tree) -> race-free
  }
}

// ---------------- CSR build: scan of (deg_bu - 1); dinv folded in ----------------
__global__ __launch_bounds__(TPB) void k_scan1(const int* __restrict__ deg_td,
    const int* __restrict__ deg_bu, float* dinv_td, float* dinv_bu,
    int* bsum, int N) {
  __shared__ int s[TPB];
  int i = blockIdx.x * TPB + threadIdx.x;
  int d = (i < N) ? deg_bu[i] : 1;
  s[threadIdx.x] = d - 1;
  if (i < N) {
    dinv_td[i] = rsqrtf((float)deg_td[i]);
    dinv_bu[i] = rsqrtf((float)d);
  }
  __syncthreads();
  for (int off = TPB / 2; off > 0; off >>= 1) {
    if (threadIdx.x < off) s[threadIdx.x] += s[threadIdx.x + off];
    __syncthreads();
  }
  if (threadIdx.x == 0) bsum[blockIdx.x] = s[0];
}

__global__ __launch_bounds__(1024) void k_scan2(int* bsum, int NB) {
  __shared__ int s[1024];
  int t = threadIdx.x;
  int own = (t < NB) ? bsum[t] : 0;
  s[t] = own;
  __syncthreads();
  for (int off = 1; off < 1024; off <<= 1) {
    int v = (t >= off) ? s[t - off] : 0;
    __syncthreads();
    s[t] += v;
    __syncthreads();
  }
  if (t < NB) bsum[t] = s[t] - own;  // exclusive
}

__global__ __launch_bounds__(TPB) void k_scan3(const int* __restrict__ deg,
    const int* __restrict__ bsum, int* offs, int* cursor, int N) {
  __shared__ int s[TPB];
  int t = threadIdx.x;
  int i = blockIdx.x * TPB + t;
  int v = (i < N) ? deg[i] - 1 : 0;
  s[t] = v;
  __syncthreads();
  for (int off = 1; off < TPB; off <<= 1) {
    int u = (t >= off) ? s[t - off] : 0;
    __syncthreads();
    s[t] += u;
    __syncthreads();
  }
  int excl = bsum[blockIdx.x] + s[t] - v;
  if (i < N) {
    offs[i] = excl;
    cursor[i] = excl;
    if (i == N - 1) offs[N] = excl + v;
  }
}

__global__ __launch_bounds__(TPB) void k_fill(const int* __restrict__ s,
    const int* __restrict__ d, int* cursor, int* childs, int E) {
  int e = blockIdx.x * TPB + threadIdx.x;
  if (e < E) {
    int pos = atomicAdd(&cursor[s[e]], 1);
    childs[pos] = d[e];
  }
}

// ---------------- root projection (f32, tiny) ----------------
__global__ __launch_bounds__(64) void k_root(const float* __restrict__ x,
    const int* __restrict__ first, const float* __restrict__ W2_td,
    const float* __restrict__ W2_bu, float* R_td, float* R_bu, int F, int H) {
  __shared__ float xr[256];
  int g = blockIdx.x;
  int c = blockIdx.y * 64 + threadIdx.x;
  int root = first[g];
  for (int k = threadIdx.x; k < F; k += 64) xr[k] = fmaxf(x[(size_t)root * F + k], 0.f);
  __syncthreads();
  float atd = 0.f, abu = 0.f;
  for (int k = 0; k < F; ++k) {
    float v = xr[k];
    atd += v * W2_td[(size_t)(H + k) * H + c];
    abu += v * W2_bu[(size_t)(H + k) * H + c];
  }
  R_td[(size_t)g * H + c] = atd;
  R_bu[(size_t)g * H + c] = abu;
}

// ---------------- transpose-cast 4 weights in one launch ----------------
__global__ __launch_bounds__(TPB) void k_prep_w4(
    const float* __restrict__ W0, const float* __restrict__ W1,
    const float* __restrict__ W2, const float* __restrict__ W3,
    ushort* __restrict__ T0, ushort* __restrict__ T1,
    ushort* __restrict__ T2, ushort* __restrict__ T3, int K, int Nn) {
  int total = K * Nn;
  int idx = blockIdx.x * TPB + threadIdx.x;
  int w = idx / total;
  idx -= w * total;
  if (w >= 4) return;
  const float* W = (w == 0) ? W0 : (w == 1) ? W1 : (w == 2) ? W2 : W3;
  ushort* T = (w == 0) ? T0 : (w == 1) ? T1 : (w == 2) ? T2 : T3;
  int k = idx / Nn;
  int n = idx - k * Nn;
  T[(size_t)n * K + k] = f2bf(W[(size_t)k * Nn + n]);
}

// ============ layer-1 DUAL GEMM: A (f32, inline cast) staged ONCE, two B ============
__global__ __launch_bounds__(512, 2) void gemm_l1_dual(
    const float* __restrict__ X,
    const ushort* __restrict__ Bt0, const ushort* __restrict__ Bt1,
    ushort* __restrict__ C0, ushort* __restrict__ C1) {
  __shared__ ushort lA[2 * 4096];    // 16 KB
  __shared__ ushort lB0[2 * 8192];   // 32 KB
  __shared__ ushort lB1[2 * 8192];   // 32 KB
  const int tid = threadIdx.x;
  const int wid = tid >> 6;
  const int wr = wid >> 2;
  const int wc = wid & 3;
  const int lane = tid & 63;
  const int lr = lane & 15;
  const int lkq = lane >> 4;
  const int m0 = blockIdx.x * 128;

  const int arow = m0 + (tid >> 6) * 16 + (lane & 15);
  const size_t abase = (size_t)arow * 256 + lkq * 8;
  const size_t boff0 = (size_t)((tid >> 6) * 16 + lr) * 256 + lkq * 8;
  const size_t boff1 = (size_t)((8 + (tid >> 6)) * 16 + lr) * 256 + lkq * 8;
  const int cw = tid & ~63;

  float4v acc0[4][4], acc1[4][4];
#pragma unroll
  for (int rf = 0; rf < 4; ++rf)
#pragma unroll
    for (int t = 0; t < 4; ++t) { acc0[rf][t] = (float4v)0.f; acc1[rf][t] = (float4v)0.f; }

  float4 a0v, a1v;
  a0v = *(const float4*)&X[abase];
  a1v = *(const float4*)&X[abase + 4];
#if GLDS_FALLBACK
  *(uint4*)&lB0[(0 * 1024 + tid) * 8] = *(const uint4*)&Bt0[boff0];
  *(uint4*)&lB0[(0 * 1024 + 512 + tid) * 8] = *(const uint4*)&Bt0[boff1];
  *(uint4*)&lB1[(0 * 1024 + tid) * 8] = *(const uint4*)&Bt1[boff0];
  *(uint4*)&lB1[(0 * 1024 + 512 + tid) * 8] = *(const uint4*)&Bt1[boff1];
#else
  GLDS(&Bt0[boff0], &lB0[(size_t)(0 * 1024 + cw) * 8]);
  GLDS(&Bt0[boff1], &lB0[(size_t)(0 * 1024 + 512 + cw) * 8]);
  GLDS(&Bt1[boff0], &lB1[(size_t)(0 * 1024 + cw) * 8]);
  GLDS(&Bt1[boff1], &lB1[(size_t)(0 * 1024 + 512 + cw) * 8]);
#endif
  {
    ushort u[8];
    u[0] = f2bf(a0v.x); u[1] = f2bf(a0v.y); u[2] = f2bf(a0v.z); u[3] = f2bf(a0v.w);
    u[4] = f2bf(a1v.x); u[5] = f2bf(a1v.y); u[6] = f2bf(a1v.z); u[7] = f2bf(a1v.w);
    *(uint4*)&lA[(size_t)(0 * 512 + tid) * 8] = *(const uint4*)u;
  }
  __syncthreads();

#pragma unroll
  for (int t = 0; t < 8; ++t) {
    const int cur = t & 1;
    if (t < 7) {
      const int k1 = (t + 1) * 32;
      a0v = *(const float4*)&X[abase + k1];
      a1v = *(const float4*)&X[abase + k1 + 4];
#if GLDS_FALLBACK
      *(uint4*)&lB0[(size_t)((cur ^ 1) * 1024 + tid) * 8] = *(const uint4*)&Bt0[boff0 + k1];
      *(uint4*)&lB0[(size_t)((cur ^ 1) * 1024 + 512 + tid) * 8] = *(const uint4*)&Bt0[boff1 + k1];
      *(uint4*)&lB1[(size_t)((cur ^ 1) * 1024 + tid) * 8] = *(const uint4*)&Bt1[boff0 + k1];
      *(uint4*)&lB1[(size_t)((cur ^ 1) * 1024 + 512 + tid) * 8] = *(const uint4*)&Bt1[boff1 + k1];
#else
      GLDS(&Bt0[boff0 + k1], &lB0[(size_t)((cur ^ 1) * 1024 + cw) * 8]);
      GLDS(&Bt0[boff1 + k1], &lB0[(size_t)((cur ^ 1) * 1024 + 512 + cw) * 8]);
      GLDS(&Bt1[boff0 + k1], &lB1[(size_t)((cur ^ 1) * 1024 + cw) * 8]);
      GLDS(&Bt1[boff1 + k1], &lB1[(size_t)((cur ^ 1) * 1024 + 512 + cw) * 8]);
#endif
    }
    short8v af[4], bf0[4], bf1[4];
#pragma unroll
    for (int rf = 0; rf < 4; ++rf)
      af[rf] = *(const short8v*)&lA[(size_t)(cur * 512 + (wr * 4 + rf) * 64 + lane) * 8];
#pragma unroll
    for (int tt = 0; tt < 4; ++tt) {
      bf0[tt] = *(const short8v*)&lB0[(size_t)(cur * 1024 + (wc * 4 + tt) * 64 + lane) * 8];
      bf1[tt] = *(const short8v*)&lB1[(size_t)(cur * 1024 + (wc * 4 + tt) * 64 + lane) * 8];
    }
#pragma unroll
    for (int rf = 0; rf < 4; ++rf)
#pragma unroll
      for (int tt = 0; tt < 4; ++tt) {
        acc0[rf][tt] = __builtin_amdgcn_mfma_f32_16x16x32_bf16(af[rf], bf0[tt], acc0[rf][tt], 0, 0, 0);
        acc1[rf][tt] = __builtin_amdgcn_mfma_f32_16x16x32_bf16(af[rf], bf1[tt], acc1[rf][tt], 0, 0, 0);
      }
    if (t < 7) {
      ushort u[8];
      u[0] = f2bf(a0v.x); u[1] = f2bf(a0v.y); u[2] = f2bf(a0v.z); u[3] = f2bf(a0v.w);
      u[4] = f2bf(a1v.x); u[5] = f2bf(a1v.y); u[6] = f2bf(a1v.z); u[7] = f2bf(a1v.w);
      *(uint4*)&lA[(size_t)((cur ^ 1) * 512 + tid) * 8] = *(const uint4*)u;
    }
    __syncthreads();
  }

#pragma unroll
  for (int rf = 0; rf < 4; ++rf) {
#pragma unroll
    for (int r = 0; r < 4; ++r) {
      const int row = m0 + wr * 64 + rf * 16 + lkq * 4 + r;
#pragma unroll
      for (int t = 0; t < 4; ++t) {
        const int col = wc * 64 + t * 16 + lr;
        C0[(size_t)row * 256 + col] = f2bf(acc0[rf][t][r]);
        C1[(size_t)row * 256 + col] = f2bf(acc1[rf][t][r]);
      }
    }
  }
}

// ============ layer-2 GEMM with conv1 PREPASS body (BM=64 BN=256) ============
// R19 meta-staged version + T14 hoist: own-row gather loads (ox) are issued
// BEFORE the meta barrier (they depend only on blockIdx), so ~2 global-load
// latencies hide under meta staging + barrier. Parent/child loads still use
// staged meta (R20 showed direct meta loads regress).
template <bool CSR>
__device__ __forceinline__ void l2f_body(
    ushort* lA, ushort* lB, float* s_b, float* s_di, float* s_dp,
    int* s_p0, int* s_p1,
    const ushort* __restrict__ XW, const ushort* __restrict__ Bt,
    ushort* __restrict__ Cbf, const float* __restrict__ Rb,
    const int* __restrict__ batch, const int* __restrict__ parent,
    const int* __restrict__ offs, const int* __restrict__ childs,
    const float* __restrict__ dinv, const float* __restrict__ bias, int m0) {
  const int tid = threadIdx.x;
  const int wid = tid >> 6;
  const int wr = wid >> 2;        // 0..1
  const int wc = wid & 3;         // 0..3
  const int lane = tid & 63;
  const int lr = lane & 15;
  const int lkq = lane >> 4;

  // prepass thread mapping (needed early for the hoisted own-row loads)
  const int rl = tid >> 3;       // 0..63 local row
  const int o  = tid & 7;        // 32-col slab
  const int grow = m0 + rl;
  const int cbase = o * 32;

  // ---- T14 hoist: issue own-row loads NOW (no meta dependency) ----
  uint4 ox[4];
#pragma unroll
  for (int j = 0; j < 4; ++j)
    ox[j] = *(const uint4*)&XW[(size_t)grow * 256 + cbase + j * 8];

  if (tid < 64) {
    int row = m0 + tid;
    s_di[tid] = dinv[row];
    if (CSR) {
      s_p0[tid] = offs[row];
      s_p1[tid] = offs[row + 1];
    } else {
      int p = parent[row];
      s_p0[tid] = (p >= 0) ? p : 0;
      s_dp[tid] = (p >= 0) ? dinv[p] : 0.f;
    }
  }
  if (tid < 256) s_b[tid] = bias[tid];

  const size_t boff0 = (size_t)((tid >> 6) * 16 + lr) * 256 + lkq * 8;
  const size_t boff1 = (size_t)((8 + (tid >> 6)) * 16 + lr) * 256 + lkq * 8;
  const int cw = tid & ~63;
#if GLDS_FALLBACK
  *(uint4*)&lB[(size_t)(0 * 1024 + tid) * 8] = *(const uint4*)&Bt[boff0];
  *(uint4*)&lB[(size_t)(0 * 1024 + 512 + tid) * 8] = *(const uint4*)&Bt[boff1];
#else
  GLDS(&Bt[boff0], &lB[(size_t)(0 * 1024 + cw) * 8]);
  GLDS(&Bt[boff1], &lB[(size_t)(0 * 1024 + 512 + cw) * 8]);
#endif
  __syncthreads();  // meta visible

  // ---- prepass: conv1(XW) -> lA (coalesced reads, padded-group writes) ----
  {
    const float di = s_di[rl];
    float a[4][8];
    if (!CSR) {
      const int pp = s_p0[rl];
      const float dp = s_dp[rl];
      uint4 pu[4];
#pragma unroll
      for (int j = 0; j < 4; ++j)
        pu[j] = *(const uint4*)&XW[(size_t)pp * 256 + cbase + j * 8];
#pragma unroll
      for (int j = 0; j < 4; ++j) {
        const ushort* o8 = (const ushort*)&ox[j];
        const ushort* q8 = (const ushort*)&pu[j];
#pragma unroll
        for (int e = 0; e < 8; ++e)
          a[j][e] = bf2f(o8[e]) * di + bf2f(q8[e]) * dp;
      }
    } else {
#pragma unroll
      for (int j = 0; j < 4; ++j) {
        const ushort* o8 = (const ushort*)&ox[j];
#pragma unroll
        for (int e = 0; e < 8; ++e) a[j][e] = bf2f(o8[e]) * di;
      }
      const int k0 = s_p0[rl], k1 = s_p1[rl];
      for (int k = k0; k < k1; ++k) {
        int c = childs[k];
        float dc = dinv[c];
        uint4 cu[4];
#pragma unroll
        for (int j = 0; j < 4; ++j)
          cu[j] = *(const uint4*)&XW[(size_t)c * 256 + cbase + j * 8];
#pragma unroll
        for (int j = 0; j < 4; ++j) {
          const ushort* u8 = (const ushort*)&cu[j];
#pragma unroll
          for (int e = 0; e < 8; ++e) a[j][e] += bf2f(u8[e]) * dc;
        }
      }
    }
    const int rfg = rl >> 4, l15 = rl & 15;
    const int grp = rfg * 8 + o;
#pragma unroll
    for (int j = 0; j < 4; ++j) {
      ushort res[8];
#pragma unroll
      for (int e = 0; e < 8; ++e)
        res[e] = f2bf(fmaxf(s_b[cbase + j * 8 + e] + di * a[j][e], 0.f));
      *(uint4*)&lA[(size_t)(grp * 65 + j * 16 + l15) * 8] = *(const uint4*)res;
    }
  }
  __syncthreads();

  // ---- main loop: 8 K-steps, A from lA (padded groups), B double-buffered ----
  float4v acc[2][4];
#pragma unroll
  for (int rf = 0; rf < 2; ++rf)
#pragma unroll
    for (int t = 0; t < 4; ++t) acc[rf][t] = (float4v)0.f;

#pragma unroll
  for (int t = 0; t < 8; ++t) {
    const int cur = t & 1;
    if (t < 7) {
      const int k1 = (t + 1) * 32;
#if GLDS_FALLBACK
      *(uint4*)&lB[(size_t)((cur ^ 1) * 1024 + tid) * 8] = *(const uint4*)&Bt[boff0 + k1];
      *(uint4*)&lB[(size_t)((cur ^ 1) * 1024 + 512 + tid) * 8] = *(const uint4*)&Bt[boff1 + k1];
#else
      GLDS(&Bt[boff0 + k1], &lB[(size_t)((cur ^ 1) * 1024 + cw) * 8]);
      GLDS(&Bt[boff1 + k1], &lB[(size_t)((cur ^ 1) * 1024 + 512 + cw) * 8]);
#endif
    }
    short8v af[2], bfv[4];
#pragma unroll
    for (int rf = 0; rf < 2; ++rf)
      af[rf] = *(const short8v*)&lA[(size_t)((((wr * 2 + rf) * 8 + t) * 65) + lane) * 8];
#pragma unroll
    for (int tt = 0; tt < 4; ++tt)
      bfv[tt] = *(const short8v*)&lB[(size_t)(cur * 1024 + (wc * 4 + tt) * 64 + lane) * 8];
#pragma unroll
    for (int rf = 0; rf < 2; ++rf)
#pragma unroll
      for (int tt = 0; tt < 4; ++tt)
        acc[rf][tt] = __builtin_amdgcn_mfma_f32_16x16x32_bf16(af[rf], bfv[tt], acc[rf][tt], 0, 0, 0);
    __syncthreads();
  }

  // ---- epilogue: + R[batch], bf16 store ----
#pragma unroll
  for (int rf = 0; rf < 2; ++rf) {
#pragma unroll
    for (int r = 0; r < 4; ++r) {
      const int row = m0 + wr * 32 + rf * 16 + lkq * 4 + r;
      const float* rb = &Rb[(size_t)batch[row] * 256];
#pragma unroll
      for (int tt = 0; tt < 4; ++tt) {
        const int col = wc * 64 + tt * 16 + lr;
        Cbf[(size_t)row * 256 + col] = f2bf(acc[rf][tt][r] + rb[col]);
      }
    }
  }
}

// both directions in ONE dispatch (independent work, tails overlap)
__global__ __launch_bounds__(512, 2) void gemm_l2f_pair(
    const ushort* __restrict__ XW0, const ushort* __restrict__ XW1,
    const ushort* __restrict__ Bt0, const ushort* __restrict__ Bt1,
    ushort* __restrict__ C0, ushort* __restrict__ C1,
    const float* __restrict__ R0, const float* __restrict__ R1,
    const int* __restrict__ batch, const int* __restrict__ parent,
    const int* __restrict__ offs, const int* __restrict__ childs,
    const float* __restrict__ dinv0, const float* __restrict__ dinv1,
    const float* __restrict__ b0, const float* __restrict__ b1) {
  __shared__ ushort lA[32 * 65 * 8];  // 33280 B
  __shared__ ushort lB[2 * 8192];     // 32 KB
  __shared__ float s_b[256];
  __shared__ float s_di[64];
  __shared__ float s_dp[64];
  __shared__ int   s_p0[64];
  __shared__ int   s_p1[64];
  const int m0 = blockIdx.x * 64;
  if (blockIdx.y == 0)
    l2f_body<false>(lA, lB, s_b, s_di, s_dp, s_p0, s_p1,
                    XW0, Bt0, C0, R0, batch, parent, offs, childs, dinv0, b0, m0);
  else
    l2f_body<true>(lA, lB, s_b, s_di, s_dp, s_p0, s_p1,
                   XW1, Bt1, C1, R1, batch, parent, offs, childs, dinv1, b1, m0);
}

// ---------------- conv layer2 + pool body: 128 nodes/block, ILP-4, register pooling ----------------
template <bool CSR>
__device__ __forceinline__ void conv2_body(int bx, float (*s)[256],
    const ushort* __restrict__ xw, float* __restrict__ pool,
    const int* __restrict__ parent, const int* __restrict__ offs,
    const int* __restrict__ childs, const float* __restrict__ dinv,
    const float* __restrict__ bias, const int* __restrict__ batch, int N) {
  const int l = threadIdx.x & 31;
  const int c8 = l * 8;
  const int hw = threadIdx.x >> 5;
  const int base = bx * 128;
  if (base >= N) return;
  const int nmax = min(base + 128, N);
  const int g0 = batch[base];
  const bool uni = (batch[nmax - 1] == g0);
  float bseg[8];
  *(float4*)&bseg[0] = *(const float4*)(bias + c8);
  *(float4*)&bseg[4] = *(const float4*)(bias + c8 + 4);
  float acc[8];
#pragma unroll
  for (int j = 0; j < 8; ++j) acc[j] = 0.f;
  for (int it0 = 0; it0 < 16; it0 += 4) {
    uint4 own[4]; float di[4]; int aux[4], k1v[4], nds[4];
#pragma unroll
    for (int i = 0; i < 4; ++i) {
      int nd = base + (it0 + i) * 8 + hw;
      nds[i] = nd;
      int ndc = min(nd, N - 1);
      own[i] = *(const uint4*)(xw + (size_t)ndc * 256 + c8);
      di[i] = dinv[ndc];
      if (CSR) { aux[i] = offs[ndc]; k1v[i] = offs[ndc + 1]; }
      else { aux[i] = parent[ndc]; }
    }
    uint4 par[4]; float dp[4];
    if (!CSR) {
#pragma unroll
      for (int i = 0; i < 4; ++i) {
        int p = aux[i];
        int pp = p >= 0 ? p : 0;
        par[i] = *(const uint4*)(xw + (size_t)pp * 256 + c8);
        dp[i] = p >= 0 ? dinv[pp] : 0.f;
      }
    }
#pragma unroll
    for (int i = 0; i < 4; ++i) {
      if (nds[i] >= N) break;
      const ushort* o = (const ushort*)&own[i];
      float y[8];
      if (!CSR) {
        const ushort* q = (const ushort*)&par[i];
#pragma unroll
        for (int j = 0; j < 8; ++j) {
          float a = bf2f(o[j]) * di[i] + bf2f(q[j]) * dp[i];
          y[j] = fmaxf(bseg[j] + di[i] * a, 0.f);
        }
      } else {
        float a[8];
#pragma unroll
        for (int j = 0; j < 8; ++j) a[j] = bf2f(o[j]) * di[i];
        for (int k = aux[i]; k < k1v[i]; ++k) {
          int c = childs[k];
          float dc = dinv[c];
          uint4 u = *(const uint4*)(xw + (size_t)c * 256 + c8);
          const ushort* uu = (const ushort*)&u;
#pragma unroll
          for (int j = 0; j < 8; ++j) a[j] += bf2f(uu[j]) * dc;
        }
#pragma unroll
        for (int j = 0; j < 8; ++j) y[j] = fmaxf(bseg[j] + di[i] * a[j], 0.f);
      }
      if (uni) {
#pragma unroll
        for (int j = 0; j < 8; ++j) acc[j] += y[j];
      } else {
        int g = batch[nds[i]];
#pragma unroll
        for (int j = 0; j < 8; ++j) atomicAdd(&pool[(size_t)g * 256 + c8 + j], y[j]);
      }
    }
  }
  if (uni) {
    *(float4*)&s[hw][c8] = *(float4*)&acc[0];
    *(float4*)&s[hw][c8 + 4] = *(float4*)&acc[4];
    __syncthreads();
    int col = threadIdx.x;
    float v = 0.f;
#pragma unroll
    for (int q = 0; q < 8; ++q) v += s[q][col];
    atomicAdd(&pool[(size_t)g0 * 256 + col], v);
  }
}

__global__ __launch_bounds__(TPB) void k_conv2_pair(
    const ushort* __restrict__ xwA, const ushort* __restrict__ xwB,
    float* __restrict__ pool_td, float* __restrict__ pool_bu,
    const int* __restrict__ parent, const int* __restrict__ offs,
    const int* __restrict__ childs, const float* __restrict__ dinv_td,
    const float* __restrict__ dinv_bu, const float* __restrict__ b_td,
    const float* __restrict__ b_bu, const int* __restrict__ batch, int N) {
  __shared__ float s[8][256];
  const int bx = xcd_swz(blockIdx.x, gridDim.x);
  if (blockIdx.y == 0)
    conv2_body<false>(bx, s, xwA, pool_td, parent, offs, childs, dinv_td, b_td, batch, N);
  else
    conv2_body<true>(bx, s, xwB, pool_bu, parent, offs, childs, dinv_bu, b_bu, batch, N);
}

// ---------------- head ----------------
__global__ __launch_bounds__(128) void k_head(const float* __restrict__ pool_td,
    const float* __restrict__ pool_bu, const float* __restrict__ cnt,
    const float* __restrict__ Wl, const float* __restrict__ bl,
    float* __restrict__ out, int H, int C) {
  int g = blockIdx.x;
  int t = threadIdx.x;
  float inv = 1.f / cnt[g];
  float acc[8];
  for (int c = 0; c < C; ++c) acc[c] = 0.f;
  int twoH = 2 * H;
  for (int d0 = t; d0 < twoH; d0 += 128) {
    float v = (d0 < H ? pool_td[(size_t)g * H + d0] : pool_bu[(size_t)g * H + d0 - H]) * inv;
    for (int c = 0; c < C; ++c) acc[c] += v * Wl[(size_t)d0 * C + c];
  }
  __shared__ float red[128 * 8];
  for (int c = 0; c < C; ++c) red[t * C + c] = acc[c];
  __syncthreads();
  for (int off = 64; off > 0; off >>= 1) {
    if (t < off)
      for (int c = 0; c < C; ++c) red[t * C + c] += red[(t + off) * C + c];
    __syncthreads();
  }
  if (t == 0) {
    float l[8];
    float m = -1e30f;
    for (int c = 0; c < C; ++c) { l[c] = red[c] + bl[c]; m = fmaxf(m, l[c]); }
    float ssum = 0.f;
    for (int c = 0; c < C; ++c) ssum += expf(l[c] - m);
    float ls = logf(ssum);
    for (int c = 0; c < C; ++c) out[(size_t)g * C + c] = l[c] - m - ls;
  }
}

extern "C" void kernel_launch(void* const* d_in, const int* in_sizes, int n_in,
                              void* d_out, int out_size, void* d_ws, size_t ws_size,
                              hipStream_t stream) {
  const float* x     = (const float*)d_in[0];
  const int*   ei    = (const int*)d_in[1];
  const int*   batch = (const int*)d_in[2];
  const float* W1_td = (const float*)d_in[4];
  const float* b1_td = (const float*)d_in[5];
  const float* W1_bu = (const float*)d_in[6];
  const float* b1_bu = (const float*)d_in[7];
  const float* W2_td = (const float*)d_in[8];
  const float* b2_td = (const float*)d_in[9];
  const float* W2_bu = (const float*)d_in[10];
  const float* b2_bu = (const float*)d_in[11];
  const float* Wl    = (const float*)d_in[12];
  const float* bl    = (const float*)d_in[13];
  float* out = (float*)d_out;

  const int N = in_sizes[2];
  const int H = in_sizes[5];
  const int F = in_sizes[0] / N;
  const int E = in_sizes[1] / 2;
  const int C = in_sizes[13];
  const int G = out_size / C;

  const int* srcp = ei;
  const int* dstp = ei + E;

  const size_t NH = (size_t)N * H;
  const size_t KH = (size_t)F * H;

  ushort* bufA   = (ushort*)d_ws;                 // N*H  xw_td
  ushort* bufB   = bufA + NH;                     // N*H  h2_td
  ushort* bufC   = bufB + NH;                     // N*H  xw_bu
  ushort* bufD   = bufC + NH;                     // N*H  h2_bu
  ushort* Wt1_td = bufD + NH;                     // F*H each
  ushort* Wt1_bu = Wt1_td + KH;
  ushort* Wt2_td = Wt1_bu + KH;
  ushort* Wt2_bu = Wt2_td + KH;
  float* dinv_td = (float*)(Wt2_bu + KH);         // N
  float* dinv_bu = dinv_td + N;                   // N
  float* R_td    = dinv_bu + N;                   // G*H
  float* R_bu    = R_td + (size_t)G * H;
  float* pool_td = R_bu + (size_t)G * H;
  float* pool_bu = pool_td + (size_t)G * H;
  float* cnt     = pool_bu + (size_t)G * H;       // G
  int* deg_td    = (int*)(cnt + G);               // N
  int* deg_bu    = deg_td + N;                    // N
  int* parent    = deg_bu + N;                    // N
  int* offs      = parent + N;                    // N+1
  int* cursor    = offs + N + 1;                  // N
  int* childs    = cursor + N;                    // E
  int* bsum      = childs + E;                    // NB
  int* first     = bsum + 1024;                   // G
  size_t need = (size_t)((char*)(first + G) - (char*)d_ws);
  if (need > ws_size) return;

  const int nbN = (N + TPB - 1) / TPB;  // also NB for scan
  const int nbE = (E + TPB - 1) / TPB;
  const int GH = G * H;
  const int nbW4 = (int)((4 * KH + TPB - 1) / TPB);
  const dim3 gemmGrid(N / 128);
  const dim3 gemm2Grid(N / 64, 2);
  const dim3 conv2Grid((N + 127) / 128, 2);

  k_init<<<nbN, TPB, 0, stream>>>(deg_td, deg_bu, parent, pool_td, pool_bu, first, cnt, N, GH, G);
  k_stats<<<nbN, TPB, 0, stream>>>(batch, first, cnt, N, G);
  k_deg<<<nbE, TPB, 0, stream>>>(srcp, dstp, deg_td, deg_bu, parent, E);
  k_scan1<<<nbN, TPB, 0, stream>>>(deg_td, deg_bu, dinv_td, dinv_bu, bsum, N);
  k_scan2<<<1, 1024, 0, stream>>>(bsum, nbN);
  k_scan3<<<nbN, TPB, 0, stream>>>(deg_bu, bsum, offs, cursor, N);
  k_fill<<<nbE, TPB, 0, stream>>>(srcp, dstp, cursor, childs, E);

  k_root<<<dim3(G, H / 64), 64, 0, stream>>>(x, first, W2_td, W2_bu, R_td, R_bu, F, H);
  k_prep_w4<<<nbW4, TPB, 0, stream>>>(W1_td, W1_bu, W2_td, W2_bu,
                                      Wt1_td, Wt1_bu, Wt2_td, Wt2_bu, F, H);

  // ---- layer 1: DUAL fused cast + GEMM (x read once) ----
  gemm_l1_dual<<<gemmGrid, 512, 0, stream>>>(x, Wt1_td, Wt1_bu, bufA, bufC);

  // ---- layer 2: both directions, conv1 prepass fused, ONE dispatch ----
  gemm_l2f_pair<<<gemm2Grid, 512, 0, stream>>>(bufA, bufC, Wt2_td, Wt2_bu,
      bufB, bufD, R_td, R_bu, batch, parent, offs, childs,
      dinv_td, dinv_bu, b1_td, b1_bu);

  // ---- conv2 + pool both (128 nodes/block, ILP-4, XCD-swizzled) ----
  k_conv2_pair<<<conv2Grid, TPB, 0, stream>>>(bufB, bufD, pool_td, pool_bu,
      parent, offs, childs, dinv_td, dinv_bu, b2_td, b2_bu, batch, N);

  k_head<<<G, 128, 0, stream>>>(pool_td, pool_bu, cnt, Wl, bl, out, H, C);
}